// Round 1
// baseline (797.213 us; speedup 1.0000x reference)
//
#include <hip/hip_runtime.h>
#include <hip/hip_bf16.h>

typedef __attribute__((ext_vector_type(8))) __bf16 bf16x8;
typedef __attribute__((ext_vector_type(4))) float floatx4;

#define DEV static __device__ __forceinline__

DEV unsigned short f2bf(float f) {
  unsigned int u = __float_as_uint(f);
  u += 0x7fffu + ((u >> 16) & 1u);   // round-to-nearest-even
  return (unsigned short)(u >> 16);
}

DEV float wred_sum(float v) {
#pragma unroll
  for (int o = 32; o > 0; o >>= 1) v += __shfl_xor(v, o, 64);
  return v;
}

// ---------------- K1: emb = silu(t_emb) @ W_ada^T + b_ada  -> [2][4096] f32
__global__ void ada_kernel(const float* __restrict__ t_emb, const float* __restrict__ W_ada,
                           const float* __restrict__ b_ada, float* __restrict__ emb) {
  int w = threadIdx.x >> 6, lane = threadIdx.x & 63;
  int gid = blockIdx.x * 4 + w;          // 0..8191
  int b = gid >> 12, n = gid & 4095;
  const float* te = t_emb + (size_t)b * 1280;
  const float* wr = W_ada + (size_t)n * 1280;
  float acc = 0.f;
#pragma unroll
  for (int i = 0; i < 20; ++i) {
    int t = lane + i * 64;
    float x = te[t];
    float s = x / (1.f + __expf(-x));
    acc += s * wr[t];
  }
  acc = wred_sum(acc);
  if (lane == 0) emb[gid] = acc + b_ada[n];
}

// ---------------- K2: LayerNorm(ip) * (1+scale) + shift -> bf16 ip_n [1024][2048]
__global__ void ln_mod_kernel(const float* __restrict__ ip, const float* __restrict__ emb,
                              unsigned short* __restrict__ ipn) {
  int row = blockIdx.x;            // b*512 + l
  int b = row >> 9;
  const float* x = ip + (size_t)row * 2048;
  float xv[8];
  float s1 = 0.f, s2 = 0.f;
#pragma unroll
  for (int i = 0; i < 8; ++i) {
    float v = x[threadIdx.x + i * 256];
    xv[i] = v; s1 += v; s2 += v * v;
  }
  s1 = wred_sum(s1); s2 = wred_sum(s2);
  __shared__ float r1[4], r2[4];
  int w = threadIdx.x >> 6, lane = threadIdx.x & 63;
  if (lane == 0) { r1[w] = s1; r2[w] = s2; }
  __syncthreads();
  s1 = r1[0] + r1[1] + r1[2] + r1[3];
  s2 = r2[0] + r2[1] + r2[2] + r2[3];
  float mu = s1 * (1.f / 2048.f);
  float var = s2 * (1.f / 2048.f) - mu * mu;
  float rs = rsqrtf(var + 1e-6f);
  const float* sh = emb + (size_t)b * 4096;
  unsigned short* y = ipn + (size_t)row * 2048;
#pragma unroll
  for (int i = 0; i < 8; ++i) {
    int d = threadIdx.x + i * 256;
    float v = (xv[i] - mu) * rs;
    v = v * (1.f + sh[2048 + d]) + sh[d];
    y[d] = f2bf(v);
  }
}

// ---------------- K3: convert W_k_ip / W_v_ip fp32 -> bf16
struct us4 { unsigned short a, b, c, d; };
__global__ void cvtw_kernel(const float* __restrict__ wk, const float* __restrict__ wv,
                            unsigned short* __restrict__ wk16, unsigned short* __restrict__ wv16) {
  size_t i = ((size_t)blockIdx.x * 256 + threadIdx.x) * 4;
  float4 a = *(const float4*)(wk + i);
  float4 b = *(const float4*)(wv + i);
  us4 oa = { f2bf(a.x), f2bf(a.y), f2bf(a.z), f2bf(a.w) };
  us4 ob = { f2bf(b.x), f2bf(b.y), f2bf(b.z), f2bf(b.w) };
  *(us4*)(wk16 + i) = oa;
  *(us4*)(wv16 + i) = ob;
}

// ---------------- K4: C[1024,2048] = A[1024,2048]bf16 @ W[2048,2048]^T bf16 -> f32
__global__ __launch_bounds__(256) void proj_gemm(const unsigned short* __restrict__ A,
    const unsigned short* __restrict__ Wk, const unsigned short* __restrict__ Wv,
    float* __restrict__ Ck, float* __restrict__ Cv) {
  const unsigned short* Bm = blockIdx.z ? Wv : Wk;
  float* C = blockIdx.z ? Cv : Ck;
  int n0 = blockIdx.x * 128, m0 = blockIdx.y * 128;
  __shared__ __align__(16) unsigned short As[128 * 72];
  __shared__ __align__(16) unsigned short Bs[128 * 72];
  int tid = threadIdx.x, w = tid >> 6, lane = tid & 63, quad = lane >> 4, l16 = lane & 15;
  floatx4 acc[2][8];
#pragma unroll
  for (int i = 0; i < 2; ++i)
#pragma unroll
    for (int j = 0; j < 8; ++j) { floatx4 z = {0.f, 0.f, 0.f, 0.f}; acc[i][j] = z; }
  for (int kk = 0; kk < 2048; kk += 64) {
#pragma unroll
    for (int it = 0; it < 4; ++it) {
      int idx = tid + it * 256;
      int row = idx >> 3, chk = idx & 7;
      *(uint4*)&As[row * 72 + chk * 8] = *(const uint4*)&A[(size_t)(m0 + row) * 2048 + kk + chk * 8];
      *(uint4*)&Bs[row * 72 + chk * 8] = *(const uint4*)&Bm[(size_t)(n0 + row) * 2048 + kk + chk * 8];
    }
    __syncthreads();
#pragma unroll
    for (int c = 0; c < 2; ++c) {
      bf16x8 a0 = *(const bf16x8*)&As[(w * 32 + l16) * 72 + quad * 8 + c * 32];
      bf16x8 a1 = *(const bf16x8*)&As[(w * 32 + 16 + l16) * 72 + quad * 8 + c * 32];
#pragma unroll
      for (int nt = 0; nt < 8; ++nt) {
        bf16x8 bb = *(const bf16x8*)&Bs[(nt * 16 + l16) * 72 + quad * 8 + c * 32];
        acc[0][nt] = __builtin_amdgcn_mfma_f32_16x16x32_bf16(a0, bb, acc[0][nt], 0, 0, 0);
        acc[1][nt] = __builtin_amdgcn_mfma_f32_16x16x32_bf16(a1, bb, acc[1][nt], 0, 0, 0);
      }
    }
    __syncthreads();
  }
#pragma unroll
  for (int rt = 0; rt < 2; ++rt)
#pragma unroll
    for (int nt = 0; nt < 8; ++nt)
#pragma unroll
      for (int r = 0; r < 4; ++r)
        C[(size_t)(m0 + w * 32 + rt * 16 + quad * 4 + r) * 2048 + n0 + nt * 16 + l16] = acc[rt][nt][r];
}

// ---------------- K5: build Kcat/Vcat [B,H,2560,128] bf16 (rms on k side)
__global__ void kv_build(const float* __restrict__ img_key, const float* __restrict__ img_value,
                         const float* __restrict__ ipk, const float* __restrict__ ipv,
                         const float* __restrict__ w_k, const float* __restrict__ w_ipk,
                         unsigned short* __restrict__ Kc, unsigned short* __restrict__ Vc) {
  int gid = blockIdx.x;                       // ((b*16+h)*2560 + m)
  int m = gid % 2560, hh = (gid / 2560) & 15, b = gid / 40960;
  int d = threadIdx.x;
  float kv, vv, wgt;
  if (m < 2048) {
    size_t off = ((size_t)(b * 2048 + m)) * 2048 + hh * 128 + d;
    kv = img_key[off]; vv = img_value[off]; wgt = w_k[d];
  } else {
    size_t off = ((size_t)(b * 512 + (m - 2048))) * 2048 + hh * 128 + d;
    kv = ipk[off]; vv = ipv[off]; wgt = w_ipk[d];
  }
  float ss = wred_sum(kv * kv);
  __shared__ float red[2];
  if ((threadIdx.x & 63) == 0) red[threadIdx.x >> 6] = ss;
  __syncthreads();
  float tot = red[0] + red[1];
  float rs = rsqrtf(tot * (1.f / 128.f) + 1e-6f);
  size_t o = (size_t)gid * 128 + d;
  Kc[o] = f2bf(kv * rs * wgt);
  Vc[o] = f2bf(vv);
}

// ---------------- K6: Qn [B,H,2048,128] bf16 with rms
__global__ void q_build(const float* __restrict__ img_query, const float* __restrict__ w_q,
                        unsigned short* __restrict__ Qn) {
  int gid = blockIdx.x;                       // ((b*16+h)*2048 + l)
  int l = gid & 2047, hh = (gid >> 11) & 15, b = gid >> 15;
  int d = threadIdx.x;
  float qv = img_query[((size_t)(b * 2048 + l)) * 2048 + hh * 128 + d];
  float ss = wred_sum(qv * qv);
  __shared__ float red[2];
  if ((threadIdx.x & 63) == 0) red[threadIdx.x >> 6] = ss;
  __syncthreads();
  float tot = red[0] + red[1];
  float rs = rsqrtf(tot * (1.f / 128.f) + 1e-6f);
  Qn[(size_t)gid * 128 + d] = f2bf(qv * rs * w_q[d]);
}

// ---------------- K7: flash attention. Br=64 (4 waves x 16 rows), Bc=64, Dh=128.
__global__ __launch_bounds__(256) void attn_kernel(const unsigned short* __restrict__ Qn,
    const unsigned short* __restrict__ Kc, const unsigned short* __restrict__ Vc,
    float* __restrict__ out) {
  const float SCL = 0.12751744f;   // (1/sqrt(128)) * log2(e)
  int bh = blockIdx.x >> 5;        // b*16+h
  int qt = blockIdx.x & 31;
  int b = bh >> 4, hh = bh & 15;
  int tid = threadIdx.x, w = tid >> 6, lane = tid & 63, quad = lane >> 4, l16 = lane & 15;

  __shared__ __align__(16) unsigned short Kt[64 * 136];   // [m][d], pad 8
  __shared__ __align__(16) unsigned short Vt[128 * 72];   // [d][m], pad 8
  __shared__ __align__(16) unsigned short Pt[4 * 16 * 72];

  int q0 = qt * 64;
  const unsigned short* Qbase = Qn + ((size_t)bh * 2048 + q0) * 128;
  const unsigned short* Kbase = Kc + (size_t)bh * 2560 * 128;
  const unsigned short* Vbase = Vc + (size_t)bh * 2560 * 128;

  bf16x8 aq[4];
  {
    int qrow = w * 16 + l16;
#pragma unroll
    for (int c = 0; c < 4; ++c)
      aq[c] = *(const bf16x8*)&Qbase[(size_t)qrow * 128 + quad * 8 + c * 32];
  }

  floatx4 acc[8];
#pragma unroll
  for (int i = 0; i < 8; ++i) { floatx4 z = {0.f, 0.f, 0.f, 0.f}; acc[i] = z; }
  float m_i[4], l_i[4];
#pragma unroll
  for (int r = 0; r < 4; ++r) { m_i[r] = -__builtin_inff(); l_i[r] = 0.f; }

  unsigned short* Pw = Pt + w * (16 * 72);

  for (int t = 0; t < 40; ++t) {
    const unsigned short* Ksrc = Kbase + (size_t)t * 64 * 128;
    const unsigned short* Vsrc = Vbase + (size_t)t * 64 * 128;
#pragma unroll
    for (int it = 0; it < 4; ++it) {
      int idx = tid + it * 256;
      int row = idx >> 4, chk = idx & 15;
      *(uint4*)&Kt[row * 136 + chk * 8] = *(const uint4*)&Ksrc[(size_t)row * 128 + chk * 8];
      uint4 v = *(const uint4*)&Vsrc[(size_t)row * 128 + chk * 8];
      const unsigned short* vs = (const unsigned short*)&v;
#pragma unroll
      for (int i = 0; i < 8; ++i) Vt[(chk * 8 + i) * 72 + row] = vs[i];
    }
    __syncthreads();

    // S = Q K^T  (16 rows x 64 cols per wave)
    floatx4 s[4];
#pragma unroll
    for (int nt = 0; nt < 4; ++nt) {
      floatx4 z = {0.f, 0.f, 0.f, 0.f}; s[nt] = z;
#pragma unroll
      for (int c = 0; c < 4; ++c) {
        bf16x8 bk = *(const bf16x8*)&Kt[(nt * 16 + l16) * 136 + quad * 8 + c * 32];
        s[nt] = __builtin_amdgcn_mfma_f32_16x16x32_bf16(aq[c], bk, s[nt], 0, 0, 0);
      }
    }
    // online softmax
    float al[4], rsum[4];
#pragma unroll
    for (int r = 0; r < 4; ++r) {
      float v = fmaxf(fmaxf(s[0][r], s[1][r]), fmaxf(s[2][r], s[3][r]));
#pragma unroll
      for (int o = 1; o < 16; o <<= 1) v = fmaxf(v, __shfl_xor(v, o, 64));
      float mn = fmaxf(m_i[r], v * SCL);
      al[r] = exp2f(m_i[r] - mn);
      m_i[r] = mn;
      rsum[r] = 0.f;
    }
#pragma unroll
    for (int nt = 0; nt < 4; ++nt) {
#pragma unroll
      for (int r = 0; r < 4; ++r) {
        float p = exp2f(s[nt][r] * SCL - m_i[r]);
        rsum[r] += p;
        Pw[(quad * 4 + r) * 72 + nt * 16 + l16] = f2bf(p);
      }
    }
#pragma unroll
    for (int r = 0; r < 4; ++r) {
      float v = rsum[r];
#pragma unroll
      for (int o = 1; o < 16; o <<= 1) v += __shfl_xor(v, o, 64);
      l_i[r] = l_i[r] * al[r] + v;
    }
#pragma unroll
    for (int nt = 0; nt < 8; ++nt)
#pragma unroll
      for (int r = 0; r < 4; ++r) acc[nt][r] *= al[r];
    __syncthreads();
    // O += P V
    bf16x8 ap0 = *(const bf16x8*)&Pw[l16 * 72 + quad * 8];
    bf16x8 ap1 = *(const bf16x8*)&Pw[l16 * 72 + quad * 8 + 32];
#pragma unroll
    for (int nt = 0; nt < 8; ++nt) {
      bf16x8 bv0 = *(const bf16x8*)&Vt[(nt * 16 + l16) * 72 + quad * 8];
      bf16x8 bv1 = *(const bf16x8*)&Vt[(nt * 16 + l16) * 72 + quad * 8 + 32];
      acc[nt] = __builtin_amdgcn_mfma_f32_16x16x32_bf16(ap0, bv0, acc[nt], 0, 0, 0);
      acc[nt] = __builtin_amdgcn_mfma_f32_16x16x32_bf16(ap1, bv1, acc[nt], 0, 0, 0);
    }
    __syncthreads();
  }
  float inv[4];
#pragma unroll
  for (int r = 0; r < 4; ++r) inv[r] = 1.f / l_i[r];
#pragma unroll
  for (int nt = 0; nt < 8; ++nt)
#pragma unroll
    for (int r = 0; r < 4; ++r) {
      int qrow = q0 + w * 16 + quad * 4 + r;
      out[((size_t)(b * 2048 + qrow)) * 2048 + hh * 128 + nt * 16 + l16] = acc[nt][r] * inv[r];
    }
}

extern "C" void kernel_launch(void* const* d_in, const int* in_sizes, int n_in,
                              void* d_out, int out_size, void* d_ws, size_t ws_size,
                              hipStream_t stream) {
  const float* ip    = (const float*)d_in[0];
  const float* q     = (const float*)d_in[1];
  const float* k     = (const float*)d_in[2];
  const float* v     = (const float*)d_in[3];
  const float* temb  = (const float*)d_in[4];
  const float* wada  = (const float*)d_in[5];
  const float* bada  = (const float*)d_in[6];
  const float* wkip  = (const float*)d_in[7];
  const float* wvip  = (const float*)d_in[8];
  const float* w_q   = (const float*)d_in[9];
  const float* w_k   = (const float*)d_in[10];
  const float* w_ipk = (const float*)d_in[11];
  float* out = (float*)d_out;
  char* ws = (char*)d_ws;

  // Lifetime-overlapped workspace layout (75.5 MB total):
  //   emb[0,32K) ipn[32K,4.2M) wk16[4.2M,12.6M) wv16[12.6M,21.0M)  (dead after proj_gemm)
  //   Qn[0,16.7M) Kcat[16.7M,37.7M) Vcat[37.7M,58.7M)              (written after proj_gemm)
  //   ipk[58.7M,67.1M) ipv[67.1M,75.5M)
  float* emb           = (float*)(ws + 0);
  unsigned short* ipn  = (unsigned short*)(ws + 32768);
  unsigned short* wk16 = (unsigned short*)(ws + 4227072);
  unsigned short* wv16 = (unsigned short*)(ws + 12615680);
  unsigned short* Qn   = (unsigned short*)(ws + 0);
  unsigned short* Kcat = (unsigned short*)(ws + 16777216);
  unsigned short* Vcat = (unsigned short*)(ws + 37748736);
  float* ipk           = (float*)(ws + 58720256);
  float* ipv           = (float*)(ws + 67108864);

  ada_kernel<<<dim3(2048), dim3(256), 0, stream>>>(temb, wada, bada, emb);
  ln_mod_kernel<<<dim3(1024), dim3(256), 0, stream>>>(ip, emb, ipn);
  cvtw_kernel<<<dim3(4096), dim3(256), 0, stream>>>(wkip, wvip, wk16, wv16);
  proj_gemm<<<dim3(16, 8, 2), dim3(256), 0, stream>>>(ipn, wk16, wv16, ipk, ipv);
  kv_build<<<dim3(81920), dim3(128), 0, stream>>>(k, v, ipk, ipv, w_k, w_ipk, Kcat, Vcat);
  q_build<<<dim3(65536), dim3(128), 0, stream>>>(q, w_q, Qn);
  attn_kernel<<<dim3(1024), dim3(256), 0, stream>>>(Qn, Kcat, Vcat, out);
}